// Round 1
// baseline (233.172 us; speedup 1.0000x reference)
//
#include <hip/hip_runtime.h>
#include <hip/hip_bf16.h>
#include <stdint.h>

// ---------------------------------------------------------------------------
// EfficientSelfAttention (PVT SRA): B=4, N=4096, C=256, HEADS=8, hd=32, SR=2
// Pipeline: cast x -> bf16 | weight transpose+cast | im2col (permutation)
//           GEMM(Q) | GEMM(conv) | LN | GEMM(KV) | flash-attn | GEMM(proj)
// All MFMA: v_mfma_f32_16x16x32_bf16, fp32 accumulation.
// ---------------------------------------------------------------------------

typedef __attribute__((ext_vector_type(8))) short short8;
typedef __attribute__((ext_vector_type(4))) short short4v;
typedef __attribute__((ext_vector_type(4))) float f32x4;

#define AS1 __attribute__((address_space(1)))
#define AS3 __attribute__((address_space(3)))

static __device__ __forceinline__ unsigned short f2bfu(float f) {
  __hip_bfloat16 h = __float2bfloat16(f);
  unsigned short u; __builtin_memcpy(&u, &h, 2); return u;
}
static __device__ __forceinline__ float bfu2f(unsigned short u) {
  __hip_bfloat16 h; __builtin_memcpy(&h, &u, 2); return __bfloat162float(h);
}

// ---------------- cast x (f32 -> bf16), coalesced ----------------
__global__ __launch_bounds__(256) void k_cast_x(const float* __restrict__ in,
                                                unsigned short* __restrict__ out) {
  int i = blockIdx.x * 256 + threadIdx.x;          // one float4 per thread
  f32x4 v = ((const f32x4*)in)[i];
  short4v o;
  o[0] = (short)f2bfu(v[0]); o[1] = (short)f2bfu(v[1]);
  o[2] = (short)f2bfu(v[2]); o[3] = (short)f2bfu(v[3]);
  ((short4v*)out)[i] = o;
}

// ---------------- weight transpose+cast: dst[N][K] = src[K][N] ----------------
__global__ __launch_bounds__(256) void k_wt(const float* __restrict__ Wq, const float* __restrict__ Wconv,
                                            const float* __restrict__ Wkv, const float* __restrict__ Wproj,
                                            unsigned short* __restrict__ WqT, unsigned short* __restrict__ WconvT,
                                            unsigned short* __restrict__ WkvT, unsigned short* __restrict__ WprojT) {
  int i = blockIdx.x * 256 + threadIdx.x;          // 524288 total
  const float* src; unsigned short* dst; int K, N, j;
  if (i < 65536)       { src = Wq;    dst = WqT;    K = 256;  N = 256; j = i; }
  else if (i < 327680) { src = Wconv; dst = WconvT; K = 1024; N = 256; j = i - 65536; }
  else if (i < 458752) { src = Wkv;   dst = WkvT;   K = 256;  N = 512; j = i - 327680; }
  else                 { src = Wproj; dst = WprojT; K = 256;  N = 256; j = i - 458752; }
  int n = j / K, k = j % K;                        // K is a power of two
  dst[j] = f2bfu(src[(size_t)k * N + n]);
}

// ---------------- im2col: A[4096][1024] bf16 (pure permutation of x) --------
// xi[b,h,w,ci] = x[b, (w&15)*256+ci, h*4+(w>>4)]
// A[b*1024 + (h>>1)*32 + (w>>1)][(h&1)*512 + (w&1)*256 + ci] = xi[b,h,w,ci]
// Block = (b, wlow, ci-block of 64). Read x coalesced over c, LDS transpose,
// write A in 128B contiguous runs over ci.
__global__ __launch_bounds__(256) void k_im2col(const float* __restrict__ x,
                                                unsigned short* __restrict__ A) {
  __shared__ unsigned short tile[64][258];         // +2 pad: conflict-free cols
  int blk = blockIdx.x;                            // 256 blocks
  int b    = blk >> 6;
  int wlow = (blk >> 2) & 15;
  int cib  = blk & 3;
  int ci0  = cib << 6;
  int t = threadIdx.x;
  {
    int i = t >> 2, c0 = (t & 3) << 6;             // i: ci-offset row, c0: col chunk
    const float* xr = x + ((size_t)(b * 4096 + wlow * 256 + ci0 + i)) * 256 + c0;
#pragma unroll
    for (int j = 0; j < 16; ++j) {
      f32x4 v = *(const f32x4*)(xr + j * 4);
      tile[i][c0 + j*4 + 0] = f2bfu(v[0]);
      tile[i][c0 + j*4 + 1] = f2bfu(v[1]);
      tile[i][c0 + j*4 + 2] = f2bfu(v[2]);
      tile[i][c0 + j*4 + 3] = f2bfu(v[3]);
    }
  }
  __syncthreads();
  int wv = t >> 6, lane = t & 63;
#pragma unroll 4
  for (int rep = 0; rep < 64; ++rep) {
    int c = rep * 4 + wv;                          // source channel 0..255
    int h = c >> 2;
    int w = ((c & 3) << 4) + wlow;
    int row = b * 1024 + (h >> 1) * 32 + (w >> 1);
    int col = ((h & 1) << 9) + ((w & 1) << 8) + ci0 + lane;
    A[(size_t)row * 1024 + col] = tile[lane][c];
  }
}

// ---------------- GEMM: C[M][N] = A[M][K] @ Bt[N][K]^T + bias ----------------
// 128x128 tile, BK=32, 4 waves (2x2 of 64x64), global_load_lds width-16.
__global__ __launch_bounds__(256) void k_gemm(const unsigned short* __restrict__ A,
                                              const unsigned short* __restrict__ Bt,
                                              const float* __restrict__ bias,
                                              unsigned short* __restrict__ Cb,
                                              float* __restrict__ Cf,
                                              int M, int N, int K, int outf32) {
  __shared__ __attribute__((aligned(16))) unsigned short As[128 * 32];
  __shared__ __attribute__((aligned(16))) unsigned short Bs[128 * 32];
  int t = threadIdx.x;
  int wave = t >> 6, lane = t & 63;
  int m0 = blockIdx.x << 7, n0 = blockIdx.y << 7;
  int wm = (wave & 1) << 6, wn = (wave >> 1) << 6;
  int lr = lane & 15, lk = (lane >> 4) << 3;
  f32x4 acc[4][4] = {};
  for (int k0 = 0; k0 < K; k0 += 32) {
    __syncthreads();
#pragma unroll
    for (int it = 0; it < 2; ++it) {
      int c = it * 256 + t;                        // chunk 0..511, 16B each
      int row = c >> 2, kc = (c & 3) << 3;
      __builtin_amdgcn_global_load_lds((const AS1 unsigned int*)(A + (size_t)(m0 + row) * K + k0 + kc),
                                       (AS3 unsigned int*)(As + c * 8), 16, 0, 0);
      __builtin_amdgcn_global_load_lds((const AS1 unsigned int*)(Bt + (size_t)(n0 + row) * K + k0 + kc),
                                       (AS3 unsigned int*)(Bs + c * 8), 16, 0, 0);
    }
    __syncthreads();
    short8 af[4], bfr[4];
#pragma unroll
    for (int mi = 0; mi < 4; ++mi) af[mi]  = *(const short8*)(As + (wm + mi*16 + lr)*32 + lk);
#pragma unroll
    for (int ni = 0; ni < 4; ++ni) bfr[ni] = *(const short8*)(Bs + (wn + ni*16 + lr)*32 + lk);
#pragma unroll
    for (int mi = 0; mi < 4; ++mi)
#pragma unroll
      for (int ni = 0; ni < 4; ++ni)
        acc[mi][ni] = __builtin_amdgcn_mfma_f32_16x16x32_bf16(af[mi], bfr[ni], acc[mi][ni], 0, 0, 0);
  }
  int lrow = (lane >> 4) << 2, lcol = lane & 15;
#pragma unroll
  for (int mi = 0; mi < 4; ++mi) {
#pragma unroll
    for (int ni = 0; ni < 4; ++ni) {
      int gm = m0 + wm + mi*16 + lrow;
      int gn = n0 + wn + ni*16 + lcol;
      float bv = bias[gn];
#pragma unroll
      for (int r = 0; r < 4; ++r) {
        float v = acc[mi][ni][r] + bv;
        if (outf32) Cf[(size_t)(gm + r) * N + gn] = v;
        else        Cb[(size_t)(gm + r) * N + gn] = f2bfu(v);
      }
    }
  }
}

// ---------------- LayerNorm over last dim (256), one wave per row ----------
__global__ __launch_bounds__(256) void k_ln(const float* __restrict__ conv,
                                            const float* __restrict__ gamma,
                                            const float* __restrict__ beta,
                                            unsigned short* __restrict__ out) {
  int row = (blockIdx.x << 2) + (threadIdx.x >> 6);
  int lane = threadIdx.x & 63;
  const float* r = conv + (size_t)row * 256 + lane * 4;
  f32x4 v = *(const f32x4*)r;
  float s = v[0] + v[1] + v[2] + v[3];
#pragma unroll
  for (int m = 1; m < 64; m <<= 1) s += __shfl_xor(s, m);
  float mu = s * (1.f / 256.f);
  f32x4 d; float qv = 0.f;
#pragma unroll
  for (int j = 0; j < 4; ++j) { d[j] = v[j] - mu; qv += d[j] * d[j]; }
#pragma unroll
  for (int m = 1; m < 64; m <<= 1) qv += __shfl_xor(qv, m);
  float rstd = rsqrtf(qv * (1.f / 256.f) + 1e-6f);
  f32x4 g  = *(const f32x4*)(gamma + lane * 4);
  f32x4 bb = *(const f32x4*)(beta  + lane * 4);
  short4v ov;
#pragma unroll
  for (int j = 0; j < 4; ++j) ov[j] = (short)f2bfu(d[j] * rstd * g[j] + bb[j]);
  *(short4v*)(out + (size_t)row * 256 + lane * 4) = ov;
}

// ---------------- flash attention: q[16384][256], kv[4096][512] ------------
// grid (64 q-tiles, 32 bh). Block: 4 waves x 16 q-rows. kv chunk = 32.
__global__ __launch_bounds__(256) void k_attn(const unsigned short* __restrict__ q,
                                              const unsigned short* __restrict__ kv,
                                              unsigned short* __restrict__ o) {
  __shared__ __attribute__((aligned(16))) unsigned short vT[32][32];   // [d][kv_local]
  __shared__ __attribute__((aligned(16))) unsigned short P[4][16][32]; // per-wave P tile
  int bh = blockIdx.y;
  int b = bh >> 3, h = bh & 7;
  int q0 = blockIdx.x << 6;
  int t = threadIdx.x, wave = t >> 6, lane = t & 63;
  int qw = q0 + (wave << 4);
  int lr = lane & 15, lkd = lane >> 4;
  const float scale = 0.17677669529663687f;        // 32^-0.5
  short8 qf = *(const short8*)(q + ((size_t)(b * 4096 + qw + lr)) * 256 + h * 32 + lkd * 8);
  f32x4 accd0 = {0.f,0.f,0.f,0.f}, accd1 = {0.f,0.f,0.f,0.f};
  float mrow[4] = {-1e30f, -1e30f, -1e30f, -1e30f};
  float lsum[4] = {0.f, 0.f, 0.f, 0.f};
  const size_t kvbase = (size_t)(b * 1024) * 512;
  for (int kv0 = 0; kv0 < 1024; kv0 += 32) {
    __syncthreads();                               // vT free to overwrite
    {
      int kvl = t >> 3, d0 = (t & 7) << 2;         // stage vT[d][kvl]
      const unsigned short* vr = kv + kvbase + (size_t)(kv0 + kvl) * 512 + 256 + h * 32 + d0;
      short4v vv = *(const short4v*)vr;
      vT[d0+0][kvl] = (unsigned short)vv[0];
      vT[d0+1][kvl] = (unsigned short)vv[1];
      vT[d0+2][kvl] = (unsigned short)vv[2];
      vT[d0+3][kvl] = (unsigned short)vv[3];
    }
    __syncthreads();
    f32x4 s0, s1;
    {
      f32x4 z = {0.f,0.f,0.f,0.f};
      short8 kf0 = *(const short8*)(kv + kvbase + (size_t)(kv0 +      lr) * 512 + h * 32 + lkd * 8);
      short8 kf1 = *(const short8*)(kv + kvbase + (size_t)(kv0 + 16 + lr) * 512 + h * 32 + lkd * 8);
      s0 = __builtin_amdgcn_mfma_f32_16x16x32_bf16(qf, kf0, z, 0, 0, 0);
      s1 = __builtin_amdgcn_mfma_f32_16x16x32_bf16(qf, kf1, z, 0, 0, 0);
    }
    float pm[4], sum[4];
#pragma unroll
    for (int r = 0; r < 4; ++r) {
      s0[r] *= scale; s1[r] *= scale;
      pm[r] = fmaxf(s0[r], s1[r]);
    }
#pragma unroll
    for (int m = 1; m < 16; m <<= 1)
#pragma unroll
      for (int r = 0; r < 4; ++r)
        pm[r] = fmaxf(pm[r], __shfl_xor(pm[r], m));
#pragma unroll
    for (int r = 0; r < 4; ++r) {
      float mn = fmaxf(mrow[r], pm[r]);
      float alpha = __expf(mrow[r] - mn);          // first iter: exp(-inf)=0
      mrow[r] = mn;
      s0[r] = __expf(s0[r] - mn);
      s1[r] = __expf(s1[r] - mn);
      sum[r] = s0[r] + s1[r];
      lsum[r] *= alpha;
      accd0[r] *= alpha; accd1[r] *= alpha;
    }
#pragma unroll
    for (int m = 1; m < 16; m <<= 1)
#pragma unroll
      for (int r = 0; r < 4; ++r)
        sum[r] += __shfl_xor(sum[r], m);
#pragma unroll
    for (int r = 0; r < 4; ++r) {
      lsum[r] += sum[r];
      P[wave][lkd*4 + r][lr]      = f2bfu(s0[r]);  // C-layout -> A-layout via LDS
      P[wave][lkd*4 + r][16 + lr] = f2bfu(s1[r]);
    }
    short8 pf  = *(const short8*)(&P[wave][lr][lkd * 8]);
    short8 vf0 = *(const short8*)(&vT[lr][lkd * 8]);
    short8 vf1 = *(const short8*)(&vT[16 + lr][lkd * 8]);
    accd0 = __builtin_amdgcn_mfma_f32_16x16x32_bf16(pf, vf0, accd0, 0, 0, 0);
    accd1 = __builtin_amdgcn_mfma_f32_16x16x32_bf16(pf, vf1, accd1, 0, 0, 0);
  }
#pragma unroll
  for (int r = 0; r < 4; ++r) {
    float inv = 1.f / lsum[r];
    size_t orow = (size_t)(b * 4096 + qw + lkd * 4 + r) * 256 + h * 32;
    o[orow + lr]      = f2bfu(accd0[r] * inv);
    o[orow + 16 + lr] = f2bfu(accd1[r] * inv);
  }
}

// ---------------------------------------------------------------------------
extern "C" void kernel_launch(void* const* d_in, const int* in_sizes, int n_in,
                              void* d_out, int out_size, void* d_ws, size_t ws_size,
                              hipStream_t stream) {
  const float* x     = (const float*)d_in[0];
  const float* Wq    = (const float*)d_in[1];
  const float* bq    = (const float*)d_in[2];
  const float* Wconv = (const float*)d_in[3];
  const float* bconv = (const float*)d_in[4];
  const float* ln_s  = (const float*)d_in[5];
  const float* ln_b  = (const float*)d_in[6];
  const float* Wkv   = (const float*)d_in[7];
  const float* bkv   = (const float*)d_in[8];
  const float* Wproj = (const float*)d_in[9];
  const float* bproj = (const float*)d_in[10];

  char* ws = (char*)d_ws;
  unsigned short* x_bf   = (unsigned short*)(ws);                       // 8 MiB
  unsigned short* q_bf   = (unsigned short*)(ws + (size_t)(8  << 20));  // 8 MiB
  unsigned short* Aconv  = (unsigned short*)(ws + (size_t)(16 << 20));  // 8 MiB
  unsigned short* attn_o = Aconv;            // reuse: conv GEMM done before attn
  float*          conv_f = (float*)(ws + (size_t)(24 << 20));           // 4 MiB
  unsigned short* norm_b = (unsigned short*)(ws + (size_t)(28 << 20));  // 2 MiB
  unsigned short* kv_bf  = (unsigned short*)(ws + (size_t)(30 << 20));  // 4 MiB
  unsigned short* WqT    = (unsigned short*)(ws + (size_t)(34 << 20));
  unsigned short* WconvT = WqT + 65536;
  unsigned short* WkvT   = WconvT + 262144;
  unsigned short* WprojT = WkvT + 131072;

  k_cast_x<<<4096, 256, 0, stream>>>(x, x_bf);
  k_wt<<<2048, 256, 0, stream>>>(Wq, Wconv, Wkv, Wproj, WqT, WconvT, WkvT, WprojT);
  k_im2col<<<256, 256, 0, stream>>>(x, Aconv);
  // Q = x @ Wq + bq                      [16384 x 256], K=256
  k_gemm<<<dim3(128, 2), 256, 0, stream>>>(x_bf, WqT, bq, q_bf, nullptr, 16384, 256, 256, 0);
  // conv = im2col @ Wconv + bconv        [4096 x 256], K=1024  (fp32 out)
  k_gemm<<<dim3(32, 2), 256, 0, stream>>>(Aconv, WconvT, bconv, nullptr, conv_f, 4096, 256, 1024, 1);
  k_ln<<<1024, 256, 0, stream>>>(conv_f, ln_s, ln_b, norm_b);
  // kv = norm @ Wkv + bkv                [4096 x 512], K=256
  k_gemm<<<dim3(32, 4), 256, 0, stream>>>(norm_b, WkvT, bkv, kv_bf, nullptr, 4096, 512, 256, 0);
  k_attn<<<dim3(64, 32), 256, 0, stream>>>(q_bf, kv_bf, attn_o);
  // out = attn @ Wproj + bproj           [16384 x 256], K=256  (fp32 out)
  k_gemm<<<dim3(128, 2), 256, 0, stream>>>(attn_o, WprojT, bproj, nullptr, (float*)d_out, 16384, 256, 256, 1);
}

// Round 3
// 158.276 us; speedup vs baseline: 1.4732x; 1.4732x over previous
//
#include <hip/hip_runtime.h>
#include <hip/hip_bf16.h>
#include <stdint.h>

// ---------------------------------------------------------------------------
// EfficientSelfAttention (PVT SRA): B=4, N=4096, C=256, HEADS=8, hd=32, SR=2
// Pipeline: cast x -> bf16 | weight transpose+cast | im2col (permutation)
//           GEMM(Q) | GEMM(conv) | LN | GEMM(KV, writes K + V^T) |
//           flash-attn (LDS-free, swapped-MFMA, in-register softmax) | GEMM(proj)
// ---------------------------------------------------------------------------

typedef __attribute__((ext_vector_type(8))) short short8;
typedef __attribute__((ext_vector_type(4))) short short4v;
typedef __attribute__((ext_vector_type(4))) float f32x4;
typedef __attribute__((ext_vector_type(16))) float f32x16;

#define AS1 __attribute__((address_space(1)))
#define AS3 __attribute__((address_space(3)))

static __device__ __forceinline__ unsigned short f2bfu(float f) {
  __hip_bfloat16 h = __float2bfloat16(f);
  unsigned short u; __builtin_memcpy(&u, &h, 2); return u;
}

static __device__ __forceinline__ float fast_exp2(float x) {
#if __has_builtin(__builtin_amdgcn_exp2f)
  return __builtin_amdgcn_exp2f(x);
#else
  return __expf(x * 0.6931471805599453f);
#endif
}

static __device__ __forceinline__ unsigned int pkbf(float lo, float hi) {
  return ((unsigned int)f2bfu(hi) << 16) | (unsigned int)f2bfu(lo);
}

// ---------------- cast x (f32 -> bf16), coalesced ----------------
__global__ __launch_bounds__(256) void k_cast_x(const float* __restrict__ in,
                                                unsigned short* __restrict__ out) {
  int i = blockIdx.x * 256 + threadIdx.x;
  f32x4 v = ((const f32x4*)in)[i];
  short4v o;
  o[0] = (short)f2bfu(v[0]); o[1] = (short)f2bfu(v[1]);
  o[2] = (short)f2bfu(v[2]); o[3] = (short)f2bfu(v[3]);
  ((short4v*)out)[i] = o;
}

// ---------------- weight transpose+cast: dst[N][K] = src[K][N] ----------------
__global__ __launch_bounds__(256) void k_wt(const float* __restrict__ Wq, const float* __restrict__ Wconv,
                                            const float* __restrict__ Wkv, const float* __restrict__ Wproj,
                                            unsigned short* __restrict__ WqT, unsigned short* __restrict__ WconvT,
                                            unsigned short* __restrict__ WkvT, unsigned short* __restrict__ WprojT) {
  int i = blockIdx.x * 256 + threadIdx.x;          // 524288 total
  const float* src; unsigned short* dst; int K, N, j;
  if (i < 65536)       { src = Wq;    dst = WqT;    K = 256;  N = 256; j = i; }
  else if (i < 327680) { src = Wconv; dst = WconvT; K = 1024; N = 256; j = i - 65536; }
  else if (i < 458752) { src = Wkv;   dst = WkvT;   K = 256;  N = 512; j = i - 327680; }
  else                 { src = Wproj; dst = WprojT; K = 256;  N = 256; j = i - 458752; }
  int n = j / K, k = j % K;
  dst[j] = f2bfu(src[(size_t)k * N + n]);
}

// ---------------- im2col: A[4096][1024] bf16 (pure permutation of x) --------
__global__ __launch_bounds__(256) void k_im2col(const float* __restrict__ x,
                                                unsigned short* __restrict__ A) {
  __shared__ unsigned short tile[64][258];
  int blk = blockIdx.x;                            // 256 blocks
  int b    = blk >> 6;
  int wlow = (blk >> 2) & 15;
  int cib  = blk & 3;
  int ci0  = cib << 6;
  int t = threadIdx.x;
  {
    int i = t >> 2, c0 = (t & 3) << 6;
    const float* xr = x + ((size_t)(b * 4096 + wlow * 256 + ci0 + i)) * 256 + c0;
#pragma unroll
    for (int j = 0; j < 16; ++j) {
      f32x4 v = *(const f32x4*)(xr + j * 4);
      tile[i][c0 + j*4 + 0] = f2bfu(v[0]);
      tile[i][c0 + j*4 + 1] = f2bfu(v[1]);
      tile[i][c0 + j*4 + 2] = f2bfu(v[2]);
      tile[i][c0 + j*4 + 3] = f2bfu(v[3]);
    }
  }
  __syncthreads();
  int wv = t >> 6, lane = t & 63;
#pragma unroll 4
  for (int rep = 0; rep < 64; ++rep) {
    int c = rep * 4 + wv;
    int h = c >> 2;
    int w = ((c & 3) << 4) + wlow;
    int row = b * 1024 + (h >> 1) * 32 + (w >> 1);
    int col = ((h & 1) << 9) + ((w & 1) << 8) + ci0 + lane;
    A[(size_t)row * 1024 + col] = tile[lane][c];
  }
}

// ---------------- GEMM: C[M][N] = A[M][K] @ Bt[N][K]^T + bias ----------------
// mode 0: bf16 -> Cb[M][N]; mode 1: f32 -> Cf[M][N];
// mode 2 (KV): gn<256 -> Cb (=Kbuf[tok][256]); gn>=256 -> VtOut[bh][d][kv]
__global__ __launch_bounds__(256) void k_gemm(const unsigned short* __restrict__ A,
                                              const unsigned short* __restrict__ Bt,
                                              const float* __restrict__ bias,
                                              unsigned short* __restrict__ Cb,
                                              float* __restrict__ Cf,
                                              unsigned short* __restrict__ VtOut,
                                              int M, int N, int K, int mode) {
  __shared__ __attribute__((aligned(16))) unsigned short As[128 * 32];
  __shared__ __attribute__((aligned(16))) unsigned short Bs[128 * 32];
  int t = threadIdx.x;
  int wave = t >> 6, lane = t & 63;
  int m0 = blockIdx.x << 7, n0 = blockIdx.y << 7;
  int wm = (wave & 1) << 6, wn = (wave >> 1) << 6;
  int lr = lane & 15, lk = (lane >> 4) << 3;
  f32x4 acc[4][4] = {};
  for (int k0 = 0; k0 < K; k0 += 32) {
    __syncthreads();
#pragma unroll
    for (int it = 0; it < 2; ++it) {
      int c = it * 256 + t;
      int row = c >> 2, kc = (c & 3) << 3;
      __builtin_amdgcn_global_load_lds((const AS1 unsigned int*)(A + (size_t)(m0 + row) * K + k0 + kc),
                                       (AS3 unsigned int*)(As + c * 8), 16, 0, 0);
      __builtin_amdgcn_global_load_lds((const AS1 unsigned int*)(Bt + (size_t)(n0 + row) * K + k0 + kc),
                                       (AS3 unsigned int*)(Bs + c * 8), 16, 0, 0);
    }
    __syncthreads();
    short8 af[4], bfr[4];
#pragma unroll
    for (int mi = 0; mi < 4; ++mi) af[mi]  = *(const short8*)(As + (wm + mi*16 + lr)*32 + lk);
#pragma unroll
    for (int ni = 0; ni < 4; ++ni) bfr[ni] = *(const short8*)(Bs + (wn + ni*16 + lr)*32 + lk);
#pragma unroll
    for (int mi = 0; mi < 4; ++mi)
#pragma unroll
      for (int ni = 0; ni < 4; ++ni)
        acc[mi][ni] = __builtin_amdgcn_mfma_f32_16x16x32_bf16(af[mi], bfr[ni], acc[mi][ni], 0, 0, 0);
  }
  int lrow = (lane >> 4) << 2, lcol = lane & 15;
#pragma unroll
  for (int mi = 0; mi < 4; ++mi) {
#pragma unroll
    for (int ni = 0; ni < 4; ++ni) {
      int gm = m0 + wm + mi*16 + lrow;
      int gn = n0 + wn + ni*16 + lcol;
      float bv = bias[gn];
#pragma unroll
      for (int r = 0; r < 4; ++r) {
        float v = acc[mi][ni][r] + bv;
        if (mode == 0)      Cb[(size_t)(gm + r) * N + gn] = f2bfu(v);
        else if (mode == 1) Cf[(size_t)(gm + r) * N + gn] = v;
        else {
          int tok = gm + r;
          if (gn < 256) Cb[(size_t)tok * 256 + gn] = f2bfu(v);
          else {
            int hh = (gn - 256) >> 5, dd = (gn - 256) & 31;
            VtOut[(((size_t)((tok >> 10) * 8 + hh)) * 32 + dd) * 1024 + (tok & 1023)] = f2bfu(v);
          }
        }
      }
    }
  }
}

// ---------------- LayerNorm over last dim (256), one wave per row ----------
__global__ __launch_bounds__(256) void k_ln(const float* __restrict__ conv,
                                            const float* __restrict__ gamma,
                                            const float* __restrict__ beta,
                                            unsigned short* __restrict__ out) {
  int row = (blockIdx.x << 2) + (threadIdx.x >> 6);
  int lane = threadIdx.x & 63;
  const float* r = conv + (size_t)row * 256 + lane * 4;
  f32x4 v = *(const f32x4*)r;
  float s = v[0] + v[1] + v[2] + v[3];
#pragma unroll
  for (int m = 1; m < 64; m <<= 1) s += __shfl_xor(s, m);
  float mu = s * (1.f / 256.f);
  f32x4 d; float qv = 0.f;
#pragma unroll
  for (int j = 0; j < 4; ++j) { d[j] = v[j] - mu; qv += d[j] * d[j]; }
#pragma unroll
  for (int m = 1; m < 64; m <<= 1) qv += __shfl_xor(qv, m);
  float rstd = rsqrtf(qv * (1.f / 256.f) + 1e-6f);
  f32x4 g  = *(const f32x4*)(gamma + lane * 4);
  f32x4 bb = *(const f32x4*)(beta  + lane * 4);
  short4v ov;
#pragma unroll
  for (int j = 0; j < 4; ++j) ov[j] = (short)f2bfu(d[j] * rstd * g[j] + bb[j]);
  *(short4v*)(out + (size_t)row * 256 + lane * 4) = ov;
}

// ---------------- flash attention, LDS-free ---------------------------------
// grid (32 q-groups, 32 bh), 4 waves/block, each wave owns 32 q rows.
// S^T = mfma32x32x16(K, Q^T): lane&31 = q, regs = 16 kv rows R(r,hi)=(r&3)+8*(r>>2)+4*hi.
// O^T = mfma32x32x16(V^T, P^T): lane&31 = q, regs = 16 d rows. No LDS tiles, no barriers.
// Cross-half exchange via __shfl_xor(.,32) (ds_bpermute; semantics certain).
__global__ __launch_bounds__(256) void k_attn(const unsigned short* __restrict__ qb,
                                              const unsigned short* __restrict__ Kb,
                                              const unsigned short* __restrict__ Vt,
                                              unsigned short* __restrict__ o) {
  int bh = blockIdx.y;
  int b = bh >> 3, h = bh & 7;
  int wave = threadIdx.x >> 6, lane = threadIdx.x & 63;
  int q0 = (blockIdx.x * 4 + wave) * 32;
  int lq = lane & 31, hi = lane >> 5;
  const float c1 = 0.17677669529663687f * 1.4426950408889634f;  // scale * log2e
  const unsigned short* qrow = qb + (size_t)(b * 4096 + q0 + lq) * 256 + h * 32 + hi * 8;
  short8 Qf0 = *(const short8*)(qrow);        // d = hi*8 + 0..7
  short8 Qf1 = *(const short8*)(qrow + 16);   // d = 16 + hi*8 + 0..7
  const unsigned short* krow = Kb + (size_t)(b * 1024 + lq) * 256 + h * 32 + hi * 8;
  const unsigned short* vrow = Vt + ((size_t)bh * 32 + lq) * 1024 + hi * 8;
  f32x16 acc = {};
  float m2 = -1e30f, lsum = 0.f;
  for (int kv0 = 0; kv0 < 1024; kv0 += 32) {
    short8 Kf0 = *(const short8*)(krow + (size_t)kv0 * 256);
    short8 Kf1 = *(const short8*)(krow + (size_t)kv0 * 256 + 16);
    f32x16 z = {};
    f32x16 s = __builtin_amdgcn_mfma_f32_32x32x16_bf16(Kf0, Qf0, z, 0, 0, 0);
    s = __builtin_amdgcn_mfma_f32_32x32x16_bf16(Kf1, Qf1, s, 0, 0, 0);
    // row max over own 16 kv, then combine with partner half
    float t0 = fmaxf(fmaxf(s[0], s[1]),  fmaxf(s[2], s[3]));
    float t1 = fmaxf(fmaxf(s[4], s[5]),  fmaxf(s[6], s[7]));
    float t2 = fmaxf(fmaxf(s[8], s[9]),  fmaxf(s[10], s[11]));
    float t3 = fmaxf(fmaxf(s[12], s[13]), fmaxf(s[14], s[15]));
    float pmax = fmaxf(fmaxf(t0, t1), fmaxf(t2, t3)) * c1;   // log2 domain
    pmax = fmaxf(pmax, __shfl_xor(pmax, 32));
    if (__any(pmax > m2 + 8.f)) {                 // defer-max (T13)
      float mn = fmaxf(m2, pmax);
      float alpha = fast_exp2(m2 - mn);
      m2 = mn; lsum *= alpha;
#pragma unroll
      for (int r = 0; r < 16; ++r) acc[r] *= alpha;
    }
    float p[16]; float ls = 0.f;
#pragma unroll
    for (int r = 0; r < 16; ++r) { p[r] = fast_exp2(fmaf(s[r], c1, -m2)); ls += p[r]; }
    lsum += ls;
    // pack P -> bf16 pairs; exchange with partner half; assemble PV B-frags.
    // C-layout rows per lane: R(r,hi) = (r&3) + 8*(r>>2) + 4*hi.
    unsigned int X0 = pkbf(p[0],  p[1]),  X1 = pkbf(p[2],  p[3]);   // rows {0,1},{2,3}+4hi
    unsigned int Y0 = pkbf(p[4],  p[5]),  Y1 = pkbf(p[6],  p[7]);   // rows {8,9},{10,11}+4hi
    unsigned int Z0 = pkbf(p[8],  p[9]),  Z1 = pkbf(p[10], p[11]);  // rows {16,17},{18,19}+4hi
    unsigned int W0 = pkbf(p[12], p[13]), W1 = pkbf(p[14], p[15]);  // rows {24,25},{26,27}+4hi
    unsigned int pX0 = (unsigned int)__shfl_xor((int)X0, 32), pX1 = (unsigned int)__shfl_xor((int)X1, 32);
    unsigned int pY0 = (unsigned int)__shfl_xor((int)Y0, 32), pY1 = (unsigned int)__shfl_xor((int)Y1, 32);
    unsigned int pZ0 = (unsigned int)__shfl_xor((int)Z0, 32), pZ1 = (unsigned int)__shfl_xor((int)Z1, 32);
    unsigned int pW0 = (unsigned int)__shfl_xor((int)W0, 32), pW1 = (unsigned int)__shfl_xor((int)W1, 32);
    union { unsigned int u[4]; short8 s8; } f0, f1;
    // B-frag word w at lane-half hi holds chunk rows {8hi+2w, 8hi+2w+1} (f0), +16 (f1)
    f0.u[0] = hi ? pY0 : X0;  f0.u[1] = hi ? pY1 : X1;
    f0.u[2] = hi ? Y0 : pX0;  f0.u[3] = hi ? Y1 : pX1;
    f1.u[0] = hi ? pW0 : Z0;  f1.u[1] = hi ? pW1 : Z1;
    f1.u[2] = hi ? W0 : pZ0;  f1.u[3] = hi ? W1 : pZ1;
    short8 Vf0 = *(const short8*)(vrow + kv0);
    short8 Vf1 = *(const short8*)(vrow + kv0 + 16);
    acc = __builtin_amdgcn_mfma_f32_32x32x16_bf16(Vf0, f0.s8, acc, 0, 0, 0);
    acc = __builtin_amdgcn_mfma_f32_32x32x16_bf16(Vf1, f1.s8, acc, 0, 0, 0);
  }
  lsum += __shfl_xor(lsum, 32);
  float inv = 1.f / lsum;
  unsigned short* orow = o + (size_t)(b * 4096 + q0 + lq) * 256 + h * 32 + 4 * hi;
#pragma unroll
  for (int g = 0; g < 4; ++g) {
    short4v ov;
    ov[0] = (short)f2bfu(acc[4*g+0] * inv); ov[1] = (short)f2bfu(acc[4*g+1] * inv);
    ov[2] = (short)f2bfu(acc[4*g+2] * inv); ov[3] = (short)f2bfu(acc[4*g+3] * inv);
    *(short4v*)(orow + 8 * g) = ov;
  }
}

// ---------------------------------------------------------------------------
extern "C" void kernel_launch(void* const* d_in, const int* in_sizes, int n_in,
                              void* d_out, int out_size, void* d_ws, size_t ws_size,
                              hipStream_t stream) {
  const float* x     = (const float*)d_in[0];
  const float* Wq    = (const float*)d_in[1];
  const float* bq    = (const float*)d_in[2];
  const float* Wconv = (const float*)d_in[3];
  const float* bconv = (const float*)d_in[4];
  const float* ln_s  = (const float*)d_in[5];
  const float* ln_b  = (const float*)d_in[6];
  const float* Wkv   = (const float*)d_in[7];
  const float* bkv   = (const float*)d_in[8];
  const float* Wproj = (const float*)d_in[9];
  const float* bproj = (const float*)d_in[10];

  char* ws = (char*)d_ws;
  unsigned short* x_bf   = (unsigned short*)(ws);                       // 8 MiB (dead after Q GEMM)
  unsigned short* Vt     = (unsigned short*)(ws);                       // 2 MiB, written by KV GEMM
  unsigned short* q_bf   = (unsigned short*)(ws + (size_t)(8  << 20));  // 8 MiB
  unsigned short* Aconv  = (unsigned short*)(ws + (size_t)(16 << 20));  // 8 MiB
  unsigned short* attn_o = Aconv;            // reuse: conv GEMM done before attn
  float*          conv_f = (float*)(ws + (size_t)(24 << 20));           // 4 MiB
  unsigned short* norm_b = (unsigned short*)(ws + (size_t)(28 << 20));  // 2 MiB
  unsigned short* Kbuf   = (unsigned short*)(ws + (size_t)(30 << 20));  // 2 MiB
  unsigned short* WqT    = (unsigned short*)(ws + (size_t)(34 << 20));
  unsigned short* WconvT = WqT + 65536;
  unsigned short* WkvT   = WconvT + 262144;
  unsigned short* WprojT = WkvT + 131072;

  k_cast_x<<<4096, 256, 0, stream>>>(x, x_bf);
  k_wt<<<2048, 256, 0, stream>>>(Wq, Wconv, Wkv, Wproj, WqT, WconvT, WkvT, WprojT);
  k_im2col<<<256, 256, 0, stream>>>(x, Aconv);
  // Q = x @ Wq + bq                      [16384 x 256], K=256
  k_gemm<<<dim3(128, 2), 256, 0, stream>>>(x_bf, WqT, bq, q_bf, nullptr, nullptr, 16384, 256, 256, 0);
  // conv = im2col @ Wconv + bconv        [4096 x 256], K=1024  (fp32 out)
  k_gemm<<<dim3(32, 2), 256, 0, stream>>>(Aconv, WconvT, bconv, nullptr, conv_f, nullptr, 4096, 256, 1024, 1);
  k_ln<<<1024, 256, 0, stream>>>(conv_f, ln_s, ln_b, norm_b);
  // kv = norm @ Wkv + bkv                [4096 x 512], K=256; K -> Kbuf, V -> Vt
  k_gemm<<<dim3(32, 4), 256, 0, stream>>>(norm_b, WkvT, bkv, Kbuf, nullptr, Vt, 4096, 512, 256, 2);
  k_attn<<<dim3(32, 32), 256, 0, stream>>>(q_bf, Kbuf, Vt, attn_o);
  // out = attn @ Wproj + bproj           [16384 x 256], K=256  (fp32 out)
  k_gemm<<<dim3(128, 2), 256, 0, stream>>>(attn_o, WprojT, bproj, nullptr, (float*)d_out, nullptr, 16384, 256, 256, 1);
}